// Round 1
// baseline (109.503 us; speedup 1.0000x reference)
//
#include <hip/hip_runtime.h>
#include <hip/hip_bf16.h>

#define B_ 8192
#define C_ 10000
#define D_ 128
#define CPAD 10112   // 79 * 128

typedef float f32x4 __attribute__((ext_vector_type(4)));
typedef short s16x8 __attribute__((ext_vector_type(8)));

// ---------------- ws layout (float offsets) ----------------
// counts    : [0, 10240)
// sumx/cnew : [10240, 1290240)          (C*D; overwritten in-place with updated centers)
// git_row   : [1290240, 1298432)        (zeroed region ends here: 5,193,728 bytes)
// xnorm     : [1298432, 1306624)
// cent_val  : [1306624, 1314816)
// cnorm     : [1314816, 1325056)        (CPAD used, padded entries = 1e30)
// x_bf16    : byte 5,300,224 .. +2,097,152
// cnew_bf16 : byte 7,397,376 .. +2,588,672   (CPAD rows, pad rows zero)

// Kernel 1: scatter segment-sums + x prep (bf16 cast + row norms)
__global__ void scatter_xprep(const float* __restrict__ x, const int* __restrict__ labels,
                              float* __restrict__ counts, float* __restrict__ sumx,
                              float* __restrict__ xnorm, __hip_bfloat16* __restrict__ xb) {
    int i = blockIdx.x;
    int d = threadIdx.x;
    int l = labels[i];
    float v = x[i * D_ + d];
    atomicAdd(&sumx[l * D_ + d], v);
    if (d == 0) atomicAdd(&counts[l], 1.0f);
    xb[i * D_ + d] = __float2bfloat16(v);
    float s = v * v;
    #pragma unroll
    for (int m = 1; m < 64; m <<= 1) s += __shfl_xor(s, m);
    __shared__ float w2[2];
    if ((d & 63) == 0) w2[d >> 6] = s;
    __syncthreads();
    if (d == 0) xnorm[i] = w2[0] + w2[1];
}

// Kernel 2: center update (in-place into sumx slot) + bf16 cast + center norms (+ padding)
__global__ void center_update(const float* __restrict__ centers, const float* __restrict__ counts,
                              float* __restrict__ sumx_cnew, float* __restrict__ cnorm,
                              __hip_bfloat16* __restrict__ cb, const float* __restrict__ lr) {
    int c = blockIdx.x;
    int d = threadIdx.x;
    if (c >= C_) {
        cb[c * D_ + d] = __float2bfloat16(0.0f);
        if (d == 0) cnorm[c] = 1e30f;
        return;
    }
    float cnt = counts[c];
    float cv  = centers[c * D_ + d];
    float sx  = sumx_cnew[c * D_ + d];
    float delta = (cnt * cv - sx) / (1.0f + cnt);
    float cn = cv - lr[0] * delta;
    sumx_cnew[c * D_ + d] = cn;
    cb[c * D_ + d] = __float2bfloat16(cn);
    float s = cn * cn;
    #pragma unroll
    for (int m = 1; m < 64; m <<= 1) s += __shfl_xor(s, m);
    __shared__ float w2[2];
    if ((d & 63) == 0) w2[d >> 6] = s;
    __syncthreads();
    if (d == 0) cnorm[c] = w2[0] + w2[1];
}

// Kernel 3: exact fp32 labeled distance per row (one wave per row)
__global__ void center_vals_k(const float* __restrict__ x, const int* __restrict__ labels,
                              const float* __restrict__ cnew, float* __restrict__ cent_val) {
    int w = threadIdx.x >> 6, lane = threadIdx.x & 63;
    int i = blockIdx.x * 4 + w;
    int l = labels[i];
    float d1 = x[i * D_ + lane]      - cnew[l * D_ + lane];
    float d2 = x[i * D_ + lane + 64] - cnew[l * D_ + lane + 64];
    float s = d1 * d1 + d2 * d2;
    #pragma unroll
    for (int m = 1; m < 64; m <<= 1) s += __shfl_xor(s, m);
    if (lane == 0) cent_val[i] = s;
}

// Kernel 4: fused bf16 GEMM (x . c'^T) + git row-sum epilogue.
// 128x128 tile, 4 waves, each wave 64x64 = 4x4 frags of mfma_f32_16x16x32_bf16.
__global__ void __launch_bounds__(256)
gemm_git(const __hip_bfloat16* __restrict__ xb, const __hip_bfloat16* __restrict__ cb,
         const float* __restrict__ xnorm, const float* __restrict__ cnorm,
         float* __restrict__ git_row) {
    __shared__ uint4 ldsA[128 * 16];   // [row][chunk] 16B chunks, XOR-swizzled
    __shared__ uint4 ldsB[128 * 16];
    __shared__ float rowsum[128];

    int tid = threadIdx.x;
    int bm = blockIdx.y, bn = blockIdx.x;
    if (tid < 128) rowsum[tid] = 0.0f;

    const uint4* gA = (const uint4*)xb + bm * 128 * 16;   // row stride = 16 uint4
    const uint4* gB = (const uint4*)cb + bn * 128 * 16;
    #pragma unroll
    for (int p = 0; p < 8; p++) {
        int idx = tid + p * 256;
        int row = idx >> 4, ch = idx & 15;
        ldsA[row * 16 + (ch ^ (row & 7))] = gA[row * 16 + ch];
        ldsB[row * 16 + (ch ^ (row & 7))] = gB[row * 16 + ch];
    }
    __syncthreads();

    int w = tid >> 6, lane = tid & 63;
    int wm = w >> 1, wn = w & 1;
    int lr_ = lane & 15, lg = lane >> 4;

    f32x4 acc[4][4] = {};
    #pragma unroll
    for (int kk = 0; kk < 4; kk++) {
        s16x8 af[4], bfr[4];
        int kc = kk * 4 + lg;
        #pragma unroll
        for (int f = 0; f < 4; f++) {
            int rowA = wm * 64 + f * 16 + lr_;
            af[f]  = *(const s16x8*)&ldsA[rowA * 16 + (kc ^ (rowA & 7))];
            int rowB = wn * 64 + f * 16 + lr_;
            bfr[f] = *(const s16x8*)&ldsB[rowB * 16 + (kc ^ (rowB & 7))];
        }
        #pragma unroll
        for (int fm = 0; fm < 4; fm++)
            #pragma unroll
            for (int fn = 0; fn < 4; fn++)
                acc[fm][fn] = __builtin_amdgcn_mfma_f32_16x16x32_bf16(af[fm], bfr[fn], acc[fm][fn], 0, 0, 0);
    }

    // Epilogue: dist = |x|^2 + |c|^2 - 2*dot ; git = 1/(1+dist); reduce over cols.
    float cn[4];
    #pragma unroll
    for (int fn = 0; fn < 4; fn++) cn[fn] = cnorm[bn * 128 + wn * 64 + fn * 16 + lr_];
    #pragma unroll
    for (int fm = 0; fm < 4; fm++) {
        #pragma unroll
        for (int r = 0; r < 4; r++) {
            int lrow = wm * 64 + fm * 16 + lg * 4 + r;           // C/D: col=lane&15, row=(lane>>4)*4+reg
            float xn = xnorm[bm * 128 + lrow];
            float s = 0.0f;
            #pragma unroll
            for (int fn = 0; fn < 4; fn++) {
                float dist = xn + cn[fn] - 2.0f * acc[fm][fn][r];
                s += __builtin_amdgcn_rcpf(1.0f + dist);
            }
            s += __shfl_xor(s, 1); s += __shfl_xor(s, 2);
            s += __shfl_xor(s, 4); s += __shfl_xor(s, 8);
            if (lr_ == 0) atomicAdd(&rowsum[lrow], s);
        }
    }
    __syncthreads();
    if (tid < 128) atomicAdd(&git_row[bm * 128 + tid], rowsum[tid]);
}

// Kernel 5: final scalar reduction -> (center_loss, git_loss)
__global__ void final_reduce(const float* __restrict__ cent_val, const float* __restrict__ git_row,
                             float* __restrict__ out) {
    int tid = threadIdx.x;
    float cl = 0.0f, gl = 0.0f;
    for (int i = tid; i < B_; i += 256) {
        float cv = cent_val[i];
        cl += fminf(fmaxf(cv, 1e-12f), 1e12f);
        float g = git_row[i] - 1.0f / (1.0f + cv);
        gl += fminf(fmaxf(g, 1e-12f), 1e12f);
    }
    #pragma unroll
    for (int m = 1; m < 64; m <<= 1) { cl += __shfl_xor(cl, m); gl += __shfl_xor(gl, m); }
    __shared__ float scl[4], sgl[4];
    if ((tid & 63) == 0) { scl[tid >> 6] = cl; sgl[tid >> 6] = gl; }
    __syncthreads();
    if (tid == 0) {
        out[0] = (scl[0] + scl[1] + scl[2] + scl[3]) / (float)B_;
        out[1] = (sgl[0] + sgl[1] + sgl[2] + sgl[3]) / (float)B_;
    }
}

extern "C" void kernel_launch(void* const* d_in, const int* in_sizes, int n_in,
                              void* d_out, int out_size, void* d_ws, size_t ws_size,
                              hipStream_t stream) {
    const float* x       = (const float*)d_in[0];
    const int*   labels  = (const int*)d_in[1];
    const float* centers = (const float*)d_in[2];
    const float* lr      = (const float*)d_in[3];

    float* ws       = (float*)d_ws;
    float* counts   = ws;
    float* sumx     = ws + 10240;          // becomes cnew (fp32) in-place
    float* git_row  = ws + 1290240;
    float* xnorm    = ws + 1298432;
    float* cent_val = ws + 1306624;
    float* cnorm    = ws + 1314816;
    __hip_bfloat16* xb = (__hip_bfloat16*)((char*)d_ws + 5300224);
    __hip_bfloat16* cb = (__hip_bfloat16*)((char*)d_ws + 7397376);
    float* out = (float*)d_out;

    // zero accumulators: counts + sumx + git_row (contiguous prefix)
    hipMemsetAsync(d_ws, 0, (size_t)1298432 * 4, stream);

    scatter_xprep<<<B_, 128, 0, stream>>>(x, labels, counts, sumx, xnorm, xb);
    center_update<<<CPAD, 128, 0, stream>>>(centers, counts, sumx, cnorm, cb, lr);
    center_vals_k<<<B_ / 4, 256, 0, stream>>>(x, labels, sumx, cent_val);
    gemm_git<<<dim3(CPAD / 128, B_ / 128), 256, 0, stream>>>(xb, cb, xnorm, cnorm, git_row);
    final_reduce<<<1, 256, 0, stream>>>(cent_val, git_row, out);
}